// Round 11
// baseline (4040.285 us; speedup 1.0000x reference)
//
#include <hip/hip_runtime.h>

typedef unsigned short u16;
typedef unsigned int u32;
typedef unsigned long long ull;
typedef __attribute__((ext_vector_type(8))) short bf16x8;
typedef __attribute__((ext_vector_type(4))) float f32x4;
typedef __attribute__((ext_vector_type(4))) unsigned u32x4;

#define B_   128
#define T_   512
#define NOBS 256
#define H_   512
#define G4   2048
#define NACT 32
#define M_   (B_*T_)   // 65536
#define GR   8         // batch islands
#define ROWS 16        // batch rows per island
#define UN   16        // hidden units per WG
#define ZW   66        // zs row stride (floats), padded: conflict-free
#define FLAGB 0x5EED0000u

__device__ __forceinline__ float b2f(u16 s) {
  union { unsigned u; float f; } v; v.u = ((unsigned)s) << 16; return v.f;
}
__device__ __forceinline__ u16 f2b(float f) {
  union { float f; unsigned u; } v; v.f = f;
  unsigned r = v.u + 0x7FFFu + ((v.u >> 16) & 1u);
  return (u16)(r >> 16);
}
__device__ __forceinline__ float sigm(float x) { return 1.f/(1.f+__expf(-x)); }
__device__ __forceinline__ float tanh_f(float x) { return 1.f - 2.f/(1.f+__expf(2.f*x)); }

__device__ __forceinline__ void gld16(const void* g, void* ldsbase) {
#if __has_builtin(__builtin_amdgcn_global_load_lds)
  __builtin_amdgcn_global_load_lds((const __attribute__((address_space(1))) void*)g,
                                   (__attribute__((address_space(3))) void*)ldsbase, 16, 0, 0);
#else
  ((float4*)ldsbase)[threadIdx.x & 63] = *(const float4*)g;
#endif
}

// ---------------- prep kernels ----------------
// obs (B,T,NOBS) f32 -> obsT (T,B,NOBS) bf16
__global__ void k_cvt_obsT(const float* __restrict__ in, u16* __restrict__ out) {
  const long i = (long)blockIdx.x*blockDim.x + threadIdx.x;   // 8-elem chunk id
  const int k8 = (int)(i & (NOBS/8 - 1));
  const long row = i >> 5;                 // t*B + b
  const int t = (int)(row >> 7), b = (int)(row & (B_-1));
  const float* src = in + ((long)b*T_ + t)*NOBS + k8*8;
  ushort2 o[4];
  #pragma unroll
  for (int q = 0; q < 4; ++q) {
    o[q].x = f2b(src[q*2]);
    o[q].y = f2b(src[q*2+1]);
  }
  *(ushort2*)&out[i*8+0] = o[0]; *(ushort2*)&out[i*8+2] = o[1];
  *(ushort2*)&out[i*8+4] = o[2]; *(ushort2*)&out[i*8+6] = o[3];
}

// h0 (B,H) f32 -> packed bf16 pairs in plane 0 ; flags[0..511] = FLAGB
__global__ void k_inith(const float* __restrict__ h0, u16* __restrict__ hp,
                        u32* __restrict__ flags) {
  const int i = blockIdx.x*256 + threadIdx.x;   // pair id = row*256 + p
  const int row = i >> 8, p = i & 255;
  ((u32*)hp)[i] = (unsigned)f2b(h0[row*H_ + 2*p]) |
                  ((unsigned)f2b(h0[row*H_ + 2*p + 1]) << 16);
  if (i < 512) flags[i] = FLAGB;
}

// out (C,R) bf16 <- in (R,C) f32
__global__ void k_transpose(const float* __restrict__ in, u16* __restrict__ out, int R, int C) {
  int i = blockIdx.x*blockDim.x + threadIdx.x;
  if (i < R*C) {
    int c = i / R, r = i - c*R;
    out[i] = f2b(in[r*C + c]);
  }
}

// ---------------- GEMM: C(M,N) = A(M,K) @ BT(N,K)^T ----------------
template<int EPI>
__global__ __launch_bounds__(256) void k_gemm_bt(const u16* __restrict__ A, const u16* __restrict__ BT,
                                                 u16* __restrict__ C, const float* __restrict__ bias,
                                                 int M, int N, int K)
{
  __shared__ u16 As[128*64];
  __shared__ u16 Bs[128*64];
  const int tid = threadIdx.x, wv = tid >> 6, lane = tid & 63;
  const int ntile = N >> 7;
  const int tm = blockIdx.x / ntile, tn = blockIdx.x - tm*ntile;
  const int wr = wv >> 1, wc = wv & 1;
  f32x4 acc[4][4];
  for (int m=0;m<4;++m) for (int n=0;n<4;++n) acc[m][n] = (f32x4){0.f,0.f,0.f,0.f};
  const long abase = (long)tm*128, bbase = (long)tn*128;
  const int kit = K >> 6;
  for (int kt = 0; kt < kit; ++kt) {
    const int k0 = kt << 6;
    #pragma unroll
    for (int q = 0; q < 4; ++q) {
      int off = (wv*4+q)*1024 + lane*16;
      int row = off >> 7, colb = off & 127;
      gld16((const char*)A  + ((abase+row)*K + k0)*2 + colb, (char*)As + (wv*4+q)*1024);
      gld16((const char*)BT + ((bbase+row)*K + k0)*2 + colb, (char*)Bs + (wv*4+q)*1024);
    }
    asm volatile("s_waitcnt vmcnt(0)" ::: "memory");
    __syncthreads();
    const int kg = (lane >> 4) * 8;
    #pragma unroll
    for (int kk = 0; kk < 64; kk += 32) {
      bf16x8 af[4], bfr[4];
      #pragma unroll
      for (int m = 0; m < 4; ++m)
        af[m] = *(const bf16x8*)(As + (wr*64 + m*16 + (lane&15))*64 + kk + kg);
      #pragma unroll
      for (int n = 0; n < 4; ++n)
        bfr[n] = *(const bf16x8*)(Bs + (wc*64 + n*16 + (lane&15))*64 + kk + kg);
      #pragma unroll
      for (int m = 0; m < 4; ++m)
        #pragma unroll
        for (int n = 0; n < 4; ++n)
          acc[m][n] = __builtin_amdgcn_mfma_f32_16x16x32_bf16(af[m], bfr[n], acc[m][n], 0, 0, 0);
    }
    __syncthreads();
  }
  const int rq = (lane >> 4) * 4, cl = lane & 15;
  #pragma unroll
  for (int n = 0; n < 4; ++n) {
    const int coln = (int)bbase + wc*64 + n*16 + cl;
    const float bv = (EPI == 1) ? bias[coln] : 0.f;
    #pragma unroll
    for (int m = 0; m < 4; ++m) {
      const long rowb = abase + wr*64 + m*16 + rq;
      #pragma unroll
      for (int q = 0; q < 4; ++q) {
        float v = acc[m][n][q];
        if (EPI == 1) v = fmaxf(v + bv, 0.f);
        C[(rowb+q)*(long)N + coln] = f2b(v);
      }
    }
  }
}

// ---------------- persistent LSTM scan, v8: r8 skeleton, latency-shaved ----------------
// grid 256 (1 WG/CU via LDS clamp) = 8 islands x 32 unit-slices. Producer: per
// epilogue WAVE: data stores -> vmcnt(0) -> lane0 flag (64 flags/island, no WG
// barrier). Consumer: dual-slot pipelined flag poll (counted vmcnt), then ONE
// 8x16B bulk load whose RTT is covered by phase-X MFMAs. obs prefetch distance
// 2, issued off all wait paths. c-state & biases in registers.
__global__ __launch_bounds__(256, 1) void k_scan(
    const u16* __restrict__ obsT, const u16* __restrict__ WxT, const u16* __restrict__ WhT,
    const float* __restrict__ bvec, const float* __restrict__ c0f,
    u16* __restrict__ hp, u32* __restrict__ flags,
    u16* __restrict__ ys, float* __restrict__ outh, float* __restrict__ outc)
{
  __shared__ float zs[2][16*ZW];
  __shared__ char pad_[98304];     // occupancy clamp: exactly 1 WG/CU

  const int tid = threadIdx.x, wv = tid >> 6, lane = tid & 63;
  const int wg = blockIdx.x, isl = wg & (GR-1), cg = wg >> 3;
  const int rb0 = isl*ROWS, S0 = cg*UN;
  ((volatile char*)pad_)[tid] = 0;

  const int kh = wv >> 1, ch = wv & 1;
  const int C0 = ch*32;
  const int lq = lane >> 4, l15 = lane & 15;
  const int arow = rb0 + l15;

  // B-fragments (compiler schedules reloads into wait windows as needed)
  const int j0 = C0 + l15, j1 = j0 + 16;
  const long w0 = (long)((j0 >> 4)*H_ + S0 + (j0 & 15));
  const long w1 = (long)((j1 >> 4)*H_ + S0 + (j1 & 15));
  bf16x8 wbx[4][2], wbh[8][2];
  #pragma unroll
  for (int ks = 0; ks < 4; ++ks) {
    const long k = (long)kh*128 + ks*32 + lq*8;
    wbx[ks][0] = *(const bf16x8*)(WxT + w0*NOBS + k);
    wbx[ks][1] = *(const bf16x8*)(WxT + w1*NOBS + k);
  }
  #pragma unroll
  for (int ks = 0; ks < 8; ++ks) {
    const long k = (long)kh*256 + ks*32 + lq*8;
    wbh[ks][0] = *(const bf16x8*)(WhT + w0*H_ + k);
    wbh[ks][1] = *(const bf16x8*)(WhT + w1*H_ + k);
  }

  // epilogue-thread state in REGISTERS (tid<128: rr=tid>>3, units 2pp,2pp+1)
  const int rr = tid >> 3, pp = tid & 7;
  const int sl0 = 2*pp, sl1 = 2*pp + 1;
  float cv0 = 0.f, cv1 = 0.f;
  float bi0=0,bf0=0,bg0=0,bo0=0, bi1=0,bf1=0,bg1=0,bo1=0;
  if (tid < 128) {
    cv0 = c0f[(rb0 + rr)*H_ + S0 + sl0];
    cv1 = c0f[(rb0 + rr)*H_ + S0 + sl1];
    bi0 = bvec[S0 + sl0];            bi1 = bvec[S0 + sl1];
    bf0 = bvec[H_ + S0 + sl0];       bf1 = bvec[H_ + S0 + sl1];
    bg0 = bvec[2*H_ + S0 + sl0];     bg1 = bvec[2*H_ + S0 + sl1];
    bo0 = bvec[3*H_ + S0 + sl0];     bo1 = bvec[3*H_ + S0 + sl1];
  }

  const long fofs = (long)arow*H_ + kh*256 + lq*8;   // bulk fragment offset (u16)
  const u32* fp = flags + isl*64 + lane;             // 1 flag per lane (cg*2+w)

  // obs fragments: distance-2 prefetch, parity registers
  bf16x8 axA[4], axB[4];
  {
    const u16* A0 = obsT + (long)arow*NOBS + kh*128 + lq*8;            // t=0
    const u16* A1 = obsT + ((long)B_ + arow)*NOBS + kh*128 + lq*8;     // t=1
    #pragma unroll
    for (int ks = 0; ks < 4; ++ks) { axA[ks] = *(const bf16x8*)(A0 + ks*32);
                                     axB[ks] = *(const bf16x8*)(A1 + ks*32); }
  }

  auto step = [&](const int t_, bf16x8 (&AX)[4]) {
    const u32 want = FLAGB + (u32)t_;
    // --- flag poll: fast path single probe, then dual-slot pipelined spin ---
    u32 fa, fb;
    asm volatile("global_load_dword %0, %1, off sc0 sc1" : "=v"(fa) : "v"(fp));
    asm volatile("s_waitcnt vmcnt(0)" ::: "memory");
    __builtin_amdgcn_sched_barrier(0);
    fb = fa;
    if (!__all((int)(fa - want) >= 0)) {
      int spin = 1 << 17;
      for (;;) {
        asm volatile("global_load_dword %0, %1, off sc0 sc1" : "=v"(fa) : "v"(fp));
        asm volatile("global_load_dword %0, %1, off sc0 sc1" : "=v"(fb) : "v"(fp));
        asm volatile("s_waitcnt vmcnt(1)" ::: "memory");
        __builtin_amdgcn_sched_barrier(0);
        if (__all((int)(fa - want) >= 0)) break;
        asm volatile("s_waitcnt vmcnt(0)" ::: "memory");
        __builtin_amdgcn_sched_barrier(0);
        if (__all((int)(fb - want) >= 0)) break;
        if ((spin -= 2) <= 0) break;
      }
    }
    // --- issue bulk h load, cover its RTT with phase-X MFMAs ---
    union { u32x4 u; bf16x8 v; } hf[8];
    {
      const u16* haddr = hp + ((long)(t_ & 3) << 16) + fofs;
      #pragma unroll
      for (int ks = 0; ks < 8; ++ks)
        asm volatile("global_load_dwordx4 %0, %1, off offset:%2 sc0 sc1"
                     : "=v"(hf[ks].u) : "v"(haddr), "i"(ks*64));
    }
    f32x4 acc0 = {0.f,0.f,0.f,0.f}, acc1 = {0.f,0.f,0.f,0.f};
    #pragma unroll
    for (int ks = 0; ks < 4; ++ks) {
      acc0 = __builtin_amdgcn_mfma_f32_16x16x32_bf16(AX[ks], wbx[ks][0], acc0, 0, 0, 0);
      acc1 = __builtin_amdgcn_mfma_f32_16x16x32_bf16(AX[ks], wbx[ks][1], acc1, 0, 0, 0);
    }
    asm volatile("s_waitcnt vmcnt(0)" ::: "memory");
    __builtin_amdgcn_sched_barrier(0);
    asm volatile("" :: "v"(fa), "v"(fb));  // keep poll regs alive past retire
    #pragma unroll
    for (int ks = 0; ks < 8; ++ks) {
      acc0 = __builtin_amdgcn_mfma_f32_16x16x32_bf16(hf[ks].v, wbh[ks][0], acc0, 0, 0, 0);
      acc1 = __builtin_amdgcn_mfma_f32_16x16x32_bf16(hf[ks].v, wbh[ks][1], acc1, 0, 0, 0);
    }
    // --- split-K partials to LDS (D: col=lane&15, row=(lane>>4)*4+q) ---
    {
      const int zr0 = lq*4, zc = C0 + l15;
      #pragma unroll
      for (int q = 0; q < 4; ++q) {
        zs[kh][(zr0+q)*ZW + zc]      = acc0[q];
        zs[kh][(zr0+q)*ZW + zc + 16] = acc1[q];
      }
    }
    __syncthreads();
    // --- epilogue (tid<128), per-wave flag release ---
    if (tid < 128) {
      const float* z0 = &zs[0][rr*ZW];
      const float* z1 = &zs[1][rr*ZW];
      const float zi0 = z0[sl0]    + z1[sl0]    + bi0;
      const float zf0 = z0[16+sl0] + z1[16+sl0] + bf0;
      const float zg0 = z0[32+sl0] + z1[32+sl0] + bg0;
      const float zo0 = z0[48+sl0] + z1[48+sl0] + bo0;
      const float zi1 = z0[sl1]    + z1[sl1]    + bi1;
      const float zf1 = z0[16+sl1] + z1[16+sl1] + bf1;
      const float zg1 = z0[32+sl1] + z1[32+sl1] + bg1;
      const float zo1 = z0[48+sl1] + z1[48+sl1] + bo1;
      const float cn0 = sigm(zf0)*cv0 + sigm(zi0)*tanh_f(zg0);
      const float cn1 = sigm(zf1)*cv1 + sigm(zi1)*tanh_f(zg1);
      const float hv0 = sigm(zo0)*tanh_f(cn0);
      const float hv1 = sigm(zo1)*tanh_f(cn1);
      cv0 = cn0; cv1 = cn1;
      const unsigned h01 = (unsigned)f2b(hv0) | ((unsigned)f2b(hv1) << 16);
      const int bq = rb0 + rr;
      if (t_ < T_-1) {
        __hip_atomic_store((u32*)(hp + ((long)((t_+1) & 3) << 16) +
                                  (long)bq*H_ + S0 + sl0), h01,
                           __ATOMIC_RELAXED, __HIP_MEMORY_SCOPE_AGENT);
        asm volatile("s_waitcnt vmcnt(0)" ::: "memory");
        if ((tid & 63) == 0)
          __hip_atomic_store((u32*)(flags + isl*64 + cg*2 + (tid >> 6)),
                             FLAGB + (u32)(t_+1),
                             __ATOMIC_RELAXED, __HIP_MEMORY_SCOPE_AGENT);
      } else {
        outh[bq*H_ + S0 + sl0] = hv0; outh[bq*H_ + S0 + sl1] = hv1;
        outc[bq*H_ + S0 + sl0] = cn0; outc[bq*H_ + S0 + sl1] = cn1;
      }
      *(u32*)(ys + ((long)bq*T_ + t_)*H_ + S0 + sl0) = h01;
    }
    // --- obs prefetch distance 2 (off all wait paths) ---
    {
      const int tn = (t_+2 < T_) ? t_+2 : T_-1;
      const u16* Axn = obsT + ((long)tn*B_ + arow)*NOBS + kh*128 + lq*8;
      #pragma unroll
      for (int ks = 0; ks < 4; ++ks) AX[ks] = *(const bf16x8*)(Axn + ks*32);
    }
  };

  for (int t = 0; t < T_; t += 2) {
    step(t,   axA);
    step(t+1, axB);
  }
}

// ---------------- head ----------------
__global__ __launch_bounds__(256) void k_head(const u16* __restrict__ X, const u16* __restrict__ WoT,
    const float* __restrict__ bo, const float* __restrict__ amin, const float* __restrict__ amax,
    float* __restrict__ out)
{
  __shared__ u16 Ws[NACT*H_];
  __shared__ float sc[3*NACT];
  const int tid = threadIdx.x;
  #pragma unroll
  for (int q = 0; q < 8; ++q)
    ((float4*)Ws)[q*256 + tid] = ((const float4*)WoT)[q*256 + tid];
  if (tid < NACT) { sc[tid] = bo[tid]; sc[NACT+tid] = amin[tid]; sc[2*NACT+tid] = amax[tid]; }
  __syncthreads();
  const long r = (long)blockIdx.x*64 + (tid >> 2);
  const int c0 = (tid & 3)*8;
  float acc[8];
  #pragma unroll
  for (int c = 0; c < 8; ++c) acc[c] = 0.f;
  const u16* Arow = X + r*H_;
  for (int kc = 0; kc < H_/8; ++kc) {
    bf16x8 a = *(const bf16x8*)(Arow + kc*8);
    float av[8];
    #pragma unroll
    for (int j = 0; j < 8; ++j) av[j] = b2f((u16)a[j]);
    #pragma unroll
    for (int c = 0; c < 8; ++c) {
      bf16x8 w = *(const bf16x8*)(Ws + (c0+c)*H_ + kc*8);
      #pragma unroll
      for (int j = 0; j < 8; ++j) acc[c] += av[j] * b2f((u16)w[j]);
    }
  }
  #pragma unroll
  for (int c = 0; c < 8; ++c) {
    const int cc = c0 + c;
    const float y = acc[c] + sc[cc];
    const float tv = tanhf(y);
    out[r*NACT + cc] = 0.5f*(tv*(sc[2*NACT+cc]-sc[NACT+cc]) + (sc[2*NACT+cc]+sc[NACT+cc]));
  }
}

extern "C" void kernel_launch(void* const* d_in, const int* in_sizes, int n_in,
                              void* d_out, int out_size, void* d_ws, size_t ws_size,
                              hipStream_t stream) {
  const float* obs = (const float*)d_in[0];
  const float* h0  = (const float*)d_in[1];
  const float* c0  = (const float*)d_in[2];
  const float* Wx  = (const float*)d_in[3];
  const float* Wh  = (const float*)d_in[4];
  const float* bb  = (const float*)d_in[5];
  const float* W1  = (const float*)d_in[6];
  const float* b1  = (const float*)d_in[7];
  const float* W2  = (const float*)d_in[8];
  const float* b2  = (const float*)d_in[9];
  const float* Wo  = (const float*)d_in[10];
  const float* bo  = (const float*)d_in[11];
  const float* amin= (const float*)d_in[12];
  const float* amax= (const float*)d_in[13];

  char* ws = (char*)d_ws;
  // workspace layout (bytes), same proven ~172.5 MiB footprint as r8:
  u16* obsT  = (u16*)(ws + 0);                 // (T,B,NOBS) bf16, 32 MiB
  u16* ys    = (u16*)(ws + 33554432);          // (B,T,H) bf16, 64 MiB
  u16* t1    = (u16*)(ws + 100663296);         // 64 MiB (dead during scan)
  u16* t2    = (u16*)(ws + 33554432);          // alias ys (dead after W1-GEMM)
  u16* WxT   = (u16*)(ws + 167772160);         // (G4, NOBS)  1 MiB
  u16* WhT   = (u16*)(ws + 168820736);         // (G4, H)     2 MiB
  u16* W1T   = (u16*)(ws + 170917888);         // 0.5 MiB
  u16* W2T   = (u16*)(ws + 171442176);         // 0.5 MiB
  u16* WoT   = (u16*)(ws + 171966464);         // 64 KiB
  u16* hp    = (u16*)(ws + 171999232);         // 4 h planes x 128 KiB = 512 KiB
  u32* flags = (u32*)(ws + 172523520);         // 512 x 4B

  float* outA = (float*)d_out;
  float* outh = outA + (long)M_*NACT;
  float* outc = outh + B_*H_;

  k_cvt_obsT<<<M_*NOBS/8/256, 256, 0, stream>>>(obs, obsT);
  k_inith<<<B_, 256, 0, stream>>>(h0, hp, flags);     // plane 0 = h0; flags = FLAGB
  k_transpose<<<2048, 256, 0, stream>>>(Wx, WxT, NOBS, G4);
  k_transpose<<<4096, 256, 0, stream>>>(Wh, WhT, H_, G4);
  k_transpose<<<1024, 256, 0, stream>>>(W1, W1T, H_, H_);
  k_transpose<<<1024, 256, 0, stream>>>(W2, W2T, H_, H_);
  k_transpose<<<64,   256, 0, stream>>>(Wo, WoT, H_, NACT);

  // persistent scan: 256 co-resident WGs (1/CU), per-wave flag release
  k_scan<<<256, 256, 0, stream>>>(obsT, WxT, WhT, bb, c0, hp, flags, ys, outh, outc);

  // MLP head
  k_gemm_bt<1><<<(M_/128)*(H_/128), 256, 0, stream>>>(ys, W1T, t1, b1, M_, H_, H_);
  k_gemm_bt<1><<<(M_/128)*(H_/128), 256, 0, stream>>>(t1, W2T, t2, b2, M_, H_, H_);
  k_head<<<M_/64, 256, 0, stream>>>(t2, WoT, bo, amin, amax, outA);
}

// Round 13
// 3924.767 us; speedup vs baseline: 1.0294x; 1.0294x over previous
//
#include <hip/hip_runtime.h>

typedef unsigned short u16;
typedef unsigned int u32;
typedef unsigned long long ull;
typedef __attribute__((ext_vector_type(8))) short bf16x8;
typedef __attribute__((ext_vector_type(4))) float f32x4;
typedef __attribute__((ext_vector_type(4))) unsigned u32x4;

#define B_   128
#define T_   512
#define NOBS 256
#define H_   512
#define G4   2048
#define NACT 32
#define M_   (B_*T_)   // 65536
#define GR   8         // batch islands
#define ROWS 16        // batch rows per island
#define UN   16        // hidden units per WG
#define ZW   66        // zs row stride (floats), padded: conflict-free
#define FLAGB 0x5EED0000u

__device__ __forceinline__ float b2f(u16 s) {
  union { unsigned u; float f; } v; v.u = ((unsigned)s) << 16; return v.f;
}
__device__ __forceinline__ u16 f2b(float f) {
  union { float f; unsigned u; } v; v.f = f;
  unsigned r = v.u + 0x7FFFu + ((v.u >> 16) & 1u);
  return (u16)(r >> 16);
}
__device__ __forceinline__ float sigm(float x) { return 1.f/(1.f+__expf(-x)); }
__device__ __forceinline__ float tanh_f(float x) { return 1.f - 2.f/(1.f+__expf(2.f*x)); }

__device__ __forceinline__ void gld16(const void* g, void* ldsbase) {
#if __has_builtin(__builtin_amdgcn_global_load_lds)
  __builtin_amdgcn_global_load_lds((const __attribute__((address_space(1))) void*)g,
                                   (__attribute__((address_space(3))) void*)ldsbase, 16, 0, 0);
#else
  ((float4*)ldsbase)[threadIdx.x & 63] = *(const float4*)g;
#endif
}

// ---------------- prep kernels ----------------
// obs (B,T,NOBS) f32 -> obsT (T,B,NOBS) bf16
__global__ void k_cvt_obsT(const float* __restrict__ in, u16* __restrict__ out) {
  const long i = (long)blockIdx.x*blockDim.x + threadIdx.x;   // 8-elem chunk id
  const int k8 = (int)(i & (NOBS/8 - 1));
  const long row = i >> 5;                 // t*B + b
  const int t = (int)(row >> 7), b = (int)(row & (B_-1));
  const float* src = in + ((long)b*T_ + t)*NOBS + k8*8;
  ushort2 o[4];
  #pragma unroll
  for (int q = 0; q < 4; ++q) {
    o[q].x = f2b(src[q*2]);
    o[q].y = f2b(src[q*2+1]);
  }
  *(ushort2*)&out[i*8+0] = o[0]; *(ushort2*)&out[i*8+2] = o[1];
  *(ushort2*)&out[i*8+4] = o[2]; *(ushort2*)&out[i*8+6] = o[3];
}

// h0 (B,H) f32 -> packed bf16 pairs in plane 0 ; flags[0..511] = FLAGB
__global__ void k_inith(const float* __restrict__ h0, u16* __restrict__ hp,
                        u32* __restrict__ flags) {
  const int i = blockIdx.x*256 + threadIdx.x;   // pair id = row*256 + p
  const int row = i >> 8, p = i & 255;
  ((u32*)hp)[i] = (unsigned)f2b(h0[row*H_ + 2*p]) |
                  ((unsigned)f2b(h0[row*H_ + 2*p + 1]) << 16);
  if (i < 512) flags[i] = FLAGB;
}

// out (C,R) bf16 <- in (R,C) f32
__global__ void k_transpose(const float* __restrict__ in, u16* __restrict__ out, int R, int C) {
  int i = blockIdx.x*blockDim.x + threadIdx.x;
  if (i < R*C) {
    int c = i / R, r = i - c*R;
    out[i] = f2b(in[r*C + c]);
  }
}

// ---------------- GEMM: C(M,N) = A(M,K) @ BT(N,K)^T ----------------
template<int EPI>
__global__ __launch_bounds__(256) void k_gemm_bt(const u16* __restrict__ A, const u16* __restrict__ BT,
                                                 u16* __restrict__ C, const float* __restrict__ bias,
                                                 int M, int N, int K)
{
  __shared__ u16 As[128*64];
  __shared__ u16 Bs[128*64];
  const int tid = threadIdx.x, wv = tid >> 6, lane = tid & 63;
  const int ntile = N >> 7;
  const int tm = blockIdx.x / ntile, tn = blockIdx.x - tm*ntile;
  const int wr = wv >> 1, wc = wv & 1;
  f32x4 acc[4][4];
  for (int m=0;m<4;++m) for (int n=0;n<4;++n) acc[m][n] = (f32x4){0.f,0.f,0.f,0.f};
  const long abase = (long)tm*128, bbase = (long)tn*128;
  const int kit = K >> 6;
  for (int kt = 0; kt < kit; ++kt) {
    const int k0 = kt << 6;
    #pragma unroll
    for (int q = 0; q < 4; ++q) {
      int off = (wv*4+q)*1024 + lane*16;
      int row = off >> 7, colb = off & 127;
      gld16((const char*)A  + ((abase+row)*K + k0)*2 + colb, (char*)As + (wv*4+q)*1024);
      gld16((const char*)BT + ((bbase+row)*K + k0)*2 + colb, (char*)Bs + (wv*4+q)*1024);
    }
    asm volatile("s_waitcnt vmcnt(0)" ::: "memory");
    __syncthreads();
    const int kg = (lane >> 4) * 8;
    #pragma unroll
    for (int kk = 0; kk < 64; kk += 32) {
      bf16x8 af[4], bfr[4];
      #pragma unroll
      for (int m = 0; m < 4; ++m)
        af[m] = *(const bf16x8*)(As + (wr*64 + m*16 + (lane&15))*64 + kk + kg);
      #pragma unroll
      for (int n = 0; n < 4; ++n)
        bfr[n] = *(const bf16x8*)(Bs + (wc*64 + n*16 + (lane&15))*64 + kk + kg);
      #pragma unroll
      for (int m = 0; m < 4; ++m)
        #pragma unroll
        for (int n = 0; n < 4; ++n)
          acc[m][n] = __builtin_amdgcn_mfma_f32_16x16x32_bf16(af[m], bfr[n], acc[m][n], 0, 0, 0);
    }
    __syncthreads();
  }
  const int rq = (lane >> 4) * 4, cl = lane & 15;
  #pragma unroll
  for (int n = 0; n < 4; ++n) {
    const int coln = (int)bbase + wc*64 + n*16 + cl;
    const float bv = (EPI == 1) ? bias[coln] : 0.f;
    #pragma unroll
    for (int m = 0; m < 4; ++m) {
      const long rowb = abase + wr*64 + m*16 + rq;
      #pragma unroll
      for (int q = 0; q < 4; ++q) {
        float v = acc[m][n][q];
        if (EPI == 1) v = fmaxf(v + bv, 0.f);
        C[(rowb+q)*(long)N + coln] = f2b(v);
      }
    }
  }
}

// ---------------- persistent LSTM scan, v10: r8 protocol + per-wave flags + obs hoist ----
// grid 256 (1 WG/CU via LDS clamp) = 8 islands x 32 unit-slices. Agent-scope (L3)
// exchange — the ONLY correct scope (r12 disproved XCD-locality). Producer: per
// epilogue WAVE: data stores -> own vmcnt(0) drain -> lane0 flag (64 flags/island;
// no producer barrier, no tid0 serialization). Consumer: one flag per lane poll
// (__hip_atomic_load loop — compiler-scheduled waits, r11 lesson), then ONE 8x16B
// bulk load. obs prefetch issued at step TOP so its latency dies during the poll.
__global__ __launch_bounds__(256, 1) void k_scan(
    const u16* __restrict__ obsT, const u16* __restrict__ WxT, const u16* __restrict__ WhT,
    const float* __restrict__ bvec, const float* __restrict__ c0f,
    u16* __restrict__ hp, u32* __restrict__ flags,
    u16* __restrict__ ys, float* __restrict__ outh, float* __restrict__ outc)
{
  __shared__ float zs[2][16*ZW];   // split-K partials
  __shared__ float cst[256];       // cell state slice
  __shared__ float bsl[64];        // bias slice
  __shared__ char pad_[98304];     // occupancy clamp: exactly 1 WG/CU

  const int tid = threadIdx.x, wv = tid >> 6, lane = tid & 63;
  const int wg = blockIdx.x, isl = wg & (GR-1), cg = wg >> 3;
  const int rb0 = isl*ROWS, S0 = cg*UN;
  ((volatile char*)pad_)[tid] = 0;

  const int kh = wv >> 1, ch = wv & 1;
  const int C0 = ch*32;
  const int lq = lane >> 4, l15 = lane & 15;
  const int arow = rb0 + l15;

  // B-fragments (compiler schedules any reloads into wait windows)
  const int j0 = C0 + l15, j1 = j0 + 16;
  const long w0 = (long)((j0 >> 4)*H_ + S0 + (j0 & 15));
  const long w1 = (long)((j1 >> 4)*H_ + S0 + (j1 & 15));
  bf16x8 wbx[4][2], wbh[8][2];
  #pragma unroll
  for (int ks = 0; ks < 4; ++ks) {
    const long k = (long)kh*128 + ks*32 + lq*8;
    wbx[ks][0] = *(const bf16x8*)(WxT + w0*NOBS + k);
    wbx[ks][1] = *(const bf16x8*)(WxT + w1*NOBS + k);
  }
  #pragma unroll
  for (int ks = 0; ks < 8; ++ks) {
    const long k = (long)kh*256 + ks*32 + lq*8;
    wbh[ks][0] = *(const bf16x8*)(WhT + w0*H_ + k);
    wbh[ks][1] = *(const bf16x8*)(WhT + w1*H_ + k);
  }

  cst[tid] = c0f[(rb0 + (tid >> 4))*H_ + S0 + (tid & 15)];
  if (tid < 64) bsl[tid] = bvec[(tid >> 4)*H_ + S0 + (tid & 15)];
  __syncthreads();

  const long fofs = (long)arow*H_ + kh*256 + lq*8;   // bulk fragment offset (u16)
  const u32* pollp = flags + isl*64 + lane;          // one producer-wave flag per lane

  // obs fragments for t=0 (prefetched one step ahead thereafter)
  bf16x8 ax[4];
  {
    const u16* Ax = obsT + (long)arow*NOBS + kh*128 + lq*8;
    #pragma unroll
    for (int ks = 0; ks < 4; ++ks) ax[ks] = *(const bf16x8*)(Ax + ks*32);
  }

  for (int t = 0; t < T_; ++t) {
    // obs prefetch for t+1 FIRST: its HBM latency elapses under phase X + poll,
    // so the bulk-load drain below never waits on it (r8 paid this every step).
    bf16x8 axn[4];
    {
      const int tn = (t+1 < T_) ? t+1 : t;
      const u16* Axn = obsT + ((long)tn*B_ + arow)*NOBS + kh*128 + lq*8;
      #pragma unroll
      for (int ks = 0; ks < 4; ++ks) axn[ks] = *(const bf16x8*)(Axn + ks*32);
    }

    f32x4 acc0 = {0.f,0.f,0.f,0.f}, acc1 = {0.f,0.f,0.f,0.f};

    // phase X: obs_t @ Wx — retires while we wait on flags
    #pragma unroll
    for (int ks = 0; ks < 4; ++ks) {
      acc0 = __builtin_amdgcn_mfma_f32_16x16x32_bf16(ax[ks], wbx[ks][0], acc0, 0, 0, 0);
      acc1 = __builtin_amdgcn_mfma_f32_16x16x32_bf16(ax[ks], wbx[ks][1], acc1, 0, 0, 0);
    }

    // flag poll: all 64 island producer-wave flags >= want (monotone)
    {
      const u32 want = FLAGB + (u32)t;
      int spin = 1 << 20;                    // bailout: fail visibly, never hang
      for (;;) {
        const u32 f = __hip_atomic_load(pollp, __ATOMIC_RELAXED, __HIP_MEMORY_SCOPE_AGENT);
        if (__all((int)(f - want) >= 0)) break;
        if (--spin == 0) break;
      }
    }

    // h fragment loads: 8 x 16B, coherent, ONE round trip
    union { u32x4 u; bf16x8 v; } hf[8];
    {
      const u16* haddr = hp + ((long)(t & 3) << 16) + fofs;
      #pragma unroll
      for (int ks = 0; ks < 8; ++ks)
        asm volatile("global_load_dwordx4 %0, %1, off offset:%2 sc0 sc1"
                     : "=v"(hf[ks].u) : "v"(haddr), "i"(ks*64));
      asm volatile("s_waitcnt vmcnt(0)" ::: "memory");
      __builtin_amdgcn_sched_barrier(0);
    }

    // phase H: h @ Wh
    #pragma unroll
    for (int ks = 0; ks < 8; ++ks) {
      acc0 = __builtin_amdgcn_mfma_f32_16x16x32_bf16(hf[ks].v, wbh[ks][0], acc0, 0, 0, 0);
      acc1 = __builtin_amdgcn_mfma_f32_16x16x32_bf16(hf[ks].v, wbh[ks][1], acc1, 0, 0, 0);
    }
    #pragma unroll
    for (int ks = 0; ks < 4; ++ks) ax[ks] = axn[ks];

    // split-K partials to LDS  (D layout: col=lane&15, row=(lane>>4)*4+q)
    {
      const int zr0 = lq*4, zc = C0 + l15;
      #pragma unroll
      for (int q = 0; q < 4; ++q) {
        zs[kh][(zr0+q)*ZW + zc]      = acc0[q];
        zs[kh][(zr0+q)*ZW + zc + 16] = acc1[q];
      }
    }
    __syncthreads();

    // epilogue: waves 0,1 (tid<128), 2 units/thread; per-WAVE release:
    // data stores -> own-wave vmcnt(0) -> lane0 flag. zs reads precede the
    // flag in program order => poll(t+1) passing implies zs(t) reads done.
    if (tid < 128) {
      const int rr = tid >> 3, pp = tid & 7;
      float hv2[2], cn2[2];
      #pragma unroll
      for (int u = 0; u < 2; ++u) {
        const int sl = 2*pp + u;
        const float* z0 = &zs[0][rr*ZW];
        const float* z1 = &zs[1][rr*ZW];
        const float zi = z0[sl]    + z1[sl]    + bsl[sl];
        const float zf = z0[16+sl] + z1[16+sl] + bsl[16+sl];
        const float zg = z0[32+sl] + z1[32+sl] + bsl[32+sl];
        const float zo = z0[48+sl] + z1[48+sl] + bsl[48+sl];
        const float cv = cst[rr*16 + sl];
        const float cn = sigm(zf)*cv + sigm(zi)*tanh_f(zg);
        hv2[u] = sigm(zo)*tanh_f(cn);
        cn2[u] = cn;
        cst[rr*16 + sl] = cn;
      }
      const unsigned h01 = (unsigned)f2b(hv2[0]) | ((unsigned)f2b(hv2[1]) << 16);
      const int bq = rb0 + rr;
      if (t < T_-1) {
        __hip_atomic_store((u32*)(hp + ((long)((t+1) & 3) << 16) +
                                  (long)bq*H_ + S0 + 2*pp), h01,
                           __ATOMIC_RELAXED, __HIP_MEMORY_SCOPE_AGENT);
        asm volatile("s_waitcnt vmcnt(0)" ::: "memory");   // per-wave drain
        if ((tid & 63) == 0)
          __hip_atomic_store((u32*)(flags + isl*64 + cg*2 + (tid >> 6)),
                             FLAGB + (u32)(t+1),
                             __ATOMIC_RELAXED, __HIP_MEMORY_SCOPE_AGENT);
      } else {
        outh[bq*H_ + S0 + 2*pp]     = hv2[0];
        outh[bq*H_ + S0 + 2*pp + 1] = hv2[1];
        outc[bq*H_ + S0 + 2*pp]     = cn2[0];
        outc[bq*H_ + S0 + 2*pp + 1] = cn2[1];
      }
      // ys store off the critical path (after the flag)
      *(u32*)(ys + ((long)bq*T_ + t)*H_ + S0 + 2*pp) = h01;
    }
  }
}

// ---------------- head ----------------
__global__ __launch_bounds__(256) void k_head(const u16* __restrict__ X, const u16* __restrict__ WoT,
    const float* __restrict__ bo, const float* __restrict__ amin, const float* __restrict__ amax,
    float* __restrict__ out)
{
  __shared__ u16 Ws[NACT*H_];
  __shared__ float sc[3*NACT];
  const int tid = threadIdx.x;
  #pragma unroll
  for (int q = 0; q < 8; ++q)
    ((float4*)Ws)[q*256 + tid] = ((const float4*)WoT)[q*256 + tid];
  if (tid < NACT) { sc[tid] = bo[tid]; sc[NACT+tid] = amin[tid]; sc[2*NACT+tid] = amax[tid]; }
  __syncthreads();
  const long r = (long)blockIdx.x*64 + (tid >> 2);
  const int c0 = (tid & 3)*8;
  float acc[8];
  #pragma unroll
  for (int c = 0; c < 8; ++c) acc[c] = 0.f;
  const u16* Arow = X + r*H_;
  for (int kc = 0; kc < H_/8; ++kc) {
    bf16x8 a = *(const bf16x8*)(Arow + kc*8);
    float av[8];
    #pragma unroll
    for (int j = 0; j < 8; ++j) av[j] = b2f((u16)a[j]);
    #pragma unroll
    for (int c = 0; c < 8; ++c) {
      bf16x8 w = *(const bf16x8*)(Ws + (c0+c)*H_ + kc*8);
      #pragma unroll
      for (int j = 0; j < 8; ++j) acc[c] += av[j] * b2f((u16)w[j]);
    }
  }
  #pragma unroll
  for (int c = 0; c < 8; ++c) {
    const int cc = c0 + c;
    const float y = acc[c] + sc[cc];
    const float tv = tanhf(y);
    out[r*NACT + cc] = 0.5f*(tv*(sc[2*NACT+cc]-sc[NACT+cc]) + (sc[2*NACT+cc]+sc[NACT+cc]));
  }
}

extern "C" void kernel_launch(void* const* d_in, const int* in_sizes, int n_in,
                              void* d_out, int out_size, void* d_ws, size_t ws_size,
                              hipStream_t stream) {
  const float* obs = (const float*)d_in[0];
  const float* h0  = (const float*)d_in[1];
  const float* c0  = (const float*)d_in[2];
  const float* Wx  = (const float*)d_in[3];
  const float* Wh  = (const float*)d_in[4];
  const float* bb  = (const float*)d_in[5];
  const float* W1  = (const float*)d_in[6];
  const float* b1  = (const float*)d_in[7];
  const float* W2  = (const float*)d_in[8];
  const float* b2  = (const float*)d_in[9];
  const float* Wo  = (const float*)d_in[10];
  const float* bo  = (const float*)d_in[11];
  const float* amin= (const float*)d_in[12];
  const float* amax= (const float*)d_in[13];

  char* ws = (char*)d_ws;
  // workspace layout (bytes), same proven ~172.5 MiB footprint as r8:
  u16* obsT  = (u16*)(ws + 0);                 // (T,B,NOBS) bf16, 32 MiB
  u16* ys    = (u16*)(ws + 33554432);          // (B,T,H) bf16, 64 MiB
  u16* t1    = (u16*)(ws + 100663296);         // 64 MiB (dead during scan)
  u16* t2    = (u16*)(ws + 33554432);          // alias ys (dead after W1-GEMM)
  u16* WxT   = (u16*)(ws + 167772160);         // (G4, NOBS)  1 MiB
  u16* WhT   = (u16*)(ws + 168820736);         // (G4, H)     2 MiB
  u16* W1T   = (u16*)(ws + 170917888);         // 0.5 MiB
  u16* W2T   = (u16*)(ws + 171442176);         // 0.5 MiB
  u16* WoT   = (u16*)(ws + 171966464);         // 64 KiB
  u16* hp    = (u16*)(ws + 171999232);         // 4 h planes x 128 KiB = 512 KiB
  u32* flags = (u32*)(ws + 172523520);         // 512 x 4B (per-wave flags)

  float* outA = (float*)d_out;
  float* outh = outA + (long)M_*NACT;
  float* outc = outh + B_*H_;

  k_cvt_obsT<<<M_*NOBS/8/256, 256, 0, stream>>>(obs, obsT);
  k_inith<<<B_, 256, 0, stream>>>(h0, hp, flags);     // plane 0 = h0; flags = FLAGB
  k_transpose<<<2048, 256, 0, stream>>>(Wx, WxT, NOBS, G4);
  k_transpose<<<4096, 256, 0, stream>>>(Wh, WhT, H_, G4);
  k_transpose<<<1024, 256, 0, stream>>>(W1, W1T, H_, H_);
  k_transpose<<<1024, 256, 0, stream>>>(W2, W2T, H_, H_);
  k_transpose<<<64,   256, 0, stream>>>(Wo, WoT, H_, NACT);

  // persistent scan: 256 co-resident WGs (1/CU), per-wave flag release via L3
  k_scan<<<256, 256, 0, stream>>>(obsT, WxT, WhT, bb, c0, hp, flags, ys, outh, outc);

  // MLP head
  k_gemm_bt<1><<<(M_/128)*(H_/128), 256, 0, stream>>>(ys, W1T, t1, b1, M_, H_, H_);
  k_gemm_bt<1><<<(M_/128)*(H_/128), 256, 0, stream>>>(t1, W2T, t2, b2, M_, H_, H_);
  k_head<<<M_/64, 256, 0, stream>>>(t2, WoT, bo, amin, amax, outA);
}

// Round 14
// 1514.571 us; speedup vs baseline: 2.6676x; 2.5913x over previous
//
#include <hip/hip_runtime.h>

typedef unsigned short u16;
typedef unsigned int u32;
typedef unsigned long long ull;
typedef __attribute__((ext_vector_type(8))) short bf16x8;
typedef __attribute__((ext_vector_type(4))) float f32x4;
typedef __attribute__((ext_vector_type(4))) unsigned u32x4;

#define B_   128
#define T_   512
#define NOBS 256
#define H_   512
#define G4   2048
#define NACT 32
#define M_   (B_*T_)   // 65536
#define GR   8         // batch islands
#define ROWS 16        // batch rows per island
#define UN   16        // hidden units per WG
#define ZW   66        // zs row stride (floats), padded: conflict-free
#define SENT 0x7FC07FC0u   // {NaN,NaN} bf16 pair: impossible for h in (-1,1)

__device__ __forceinline__ float b2f(u16 s) {
  union { unsigned u; float f; } v; v.u = ((unsigned)s) << 16; return v.f;
}
__device__ __forceinline__ u16 f2b(float f) {
  union { float f; unsigned u; } v; v.f = f;
  unsigned r = v.u + 0x7FFFu + ((v.u >> 16) & 1u);
  return (u16)(r >> 16);
}
__device__ __forceinline__ float sigm(float x) { return 1.f/(1.f+__expf(-x)); }
__device__ __forceinline__ float tanh_f(float x) { return 1.f - 2.f/(1.f+__expf(2.f*x)); }

__device__ __forceinline__ void gld16(const void* g, void* ldsbase) {
#if __has_builtin(__builtin_amdgcn_global_load_lds)
  __builtin_amdgcn_global_load_lds((const __attribute__((address_space(1))) void*)g,
                                   (__attribute__((address_space(3))) void*)ldsbase, 16, 0, 0);
#else
  ((float4*)ldsbase)[threadIdx.x & 63] = *(const float4*)g;
#endif
}

// ---------------- prep kernels ----------------
// obs (B,T,NOBS) f32 -> obsT (T,B,NOBS) bf16
__global__ void k_cvt_obsT(const float* __restrict__ in, u16* __restrict__ out) {
  const long i = (long)blockIdx.x*blockDim.x + threadIdx.x;   // 8-elem chunk id
  const int k8 = (int)(i & (NOBS/8 - 1));
  const long row = i >> 5;                 // t*B + b
  const int t = (int)(row >> 7), b = (int)(row & (B_-1));
  const float* src = in + ((long)b*T_ + t)*NOBS + k8*8;
  ushort2 o[4];
  #pragma unroll
  for (int q = 0; q < 4; ++q) {
    o[q].x = f2b(src[q*2]);
    o[q].y = f2b(src[q*2+1]);
  }
  *(ushort2*)&out[i*8+0] = o[0]; *(ushort2*)&out[i*8+2] = o[1];
  *(ushort2*)&out[i*8+4] = o[2]; *(ushort2*)&out[i*8+6] = o[3];
}

// h planes init: plane 0 = h0 packed pairs; planes 1..7 = SENT. Grid 1024x256.
__global__ void k_inith(const float* __restrict__ h0, u16* __restrict__ hp) {
  const int i = blockIdx.x*256 + threadIdx.x;     // u32 index across 8 planes
  const int plane = i >> 15, off = i & 32767;     // 32768 u32 per plane
  u32 v;
  if (plane == 0) {
    const int row = off >> 8, p = off & 255;
    v = (unsigned)f2b(h0[row*H_ + 2*p]) | ((unsigned)f2b(h0[row*H_ + 2*p + 1]) << 16);
  } else {
    v = SENT;
  }
  ((u32*)hp)[i] = v;
}

// out (C,R) bf16 <- in (R,C) f32
__global__ void k_transpose(const float* __restrict__ in, u16* __restrict__ out, int R, int C) {
  int i = blockIdx.x*blockDim.x + threadIdx.x;
  if (i < R*C) {
    int c = i / R, r = i - c*R;
    out[i] = f2b(in[r*C + c]);
  }
}

// ---------------- GEMM: C(M,N) = A(M,K) @ BT(N,K)^T ----------------
template<int EPI>
__global__ __launch_bounds__(256) void k_gemm_bt(const u16* __restrict__ A, const u16* __restrict__ BT,
                                                 u16* __restrict__ C, const float* __restrict__ bias,
                                                 int M, int N, int K)
{
  __shared__ u16 As[128*64];
  __shared__ u16 Bs[128*64];
  const int tid = threadIdx.x, wv = tid >> 6, lane = tid & 63;
  const int ntile = N >> 7;
  const int tm = blockIdx.x / ntile, tn = blockIdx.x - tm*ntile;
  const int wr = wv >> 1, wc = wv & 1;
  f32x4 acc[4][4];
  for (int m=0;m<4;++m) for (int n=0;n<4;++n) acc[m][n] = (f32x4){0.f,0.f,0.f,0.f};
  const long abase = (long)tm*128, bbase = (long)tn*128;
  const int kit = K >> 6;
  for (int kt = 0; kt < kit; ++kt) {
    const int k0 = kt << 6;
    #pragma unroll
    for (int q = 0; q < 4; ++q) {
      int off = (wv*4+q)*1024 + lane*16;
      int row = off >> 7, colb = off & 127;
      gld16((const char*)A  + ((abase+row)*K + k0)*2 + colb, (char*)As + (wv*4+q)*1024);
      gld16((const char*)BT + ((bbase+row)*K + k0)*2 + colb, (char*)Bs + (wv*4+q)*1024);
    }
    asm volatile("s_waitcnt vmcnt(0)" ::: "memory");
    __syncthreads();
    const int kg = (lane >> 4) * 8;
    #pragma unroll
    for (int kk = 0; kk < 64; kk += 32) {
      bf16x8 af[4], bfr[4];
      #pragma unroll
      for (int m = 0; m < 4; ++m)
        af[m] = *(const bf16x8*)(As + (wr*64 + m*16 + (lane&15))*64 + kk + kg);
      #pragma unroll
      for (int n = 0; n < 4; ++n)
        bfr[n] = *(const bf16x8*)(Bs + (wc*64 + n*16 + (lane&15))*64 + kk + kg);
      #pragma unroll
      for (int m = 0; m < 4; ++m)
        #pragma unroll
        for (int n = 0; n < 4; ++n)
          acc[m][n] = __builtin_amdgcn_mfma_f32_16x16x32_bf16(af[m], bfr[n], acc[m][n], 0, 0, 0);
    }
    __syncthreads();
  }
  const int rq = (lane >> 4) * 4, cl = lane & 15;
  #pragma unroll
  for (int n = 0; n < 4; ++n) {
    const int coln = (int)bbase + wc*64 + n*16 + cl;
    const float bv = (EPI == 1) ? bias[coln] : 0.f;
    #pragma unroll
    for (int m = 0; m < 4; ++m) {
      const long rowb = abase + wr*64 + m*16 + rq;
      #pragma unroll
      for (int q = 0; q < 4; ++q) {
        float v = acc[m][n][q];
        if (EPI == 1) v = fmaxf(v + bv, 0.f);
        C[(rowb+q)*(long)N + coln] = f2b(v);
      }
    }
  }
}

// ---------------- persistent LSTM scan, v11: sentinel-in-data, 1-flight protocol -------
// r8 skeleton. 8 rotating planes; plane t&7 read at step t. Producer epilogue
// threads FIRE 4B h-stores into plane (t+1)&7 (no drain/barrier/flag) and a SENT
// store into plane (t+5)&7 (pre-cleaning the plane their own publish overwrites 4
// steps later). Consumer: the bulk 8x16B load IS the poll — retry while any word
// == SENT (h in (-1,1) can never encode it; 4B words are atomic, tearing => retry).
// Safety: island step-spread <= 1 (publish-gated); sentinel(t) drained by own step
// t+1 poll-vmcnt; producers of that plane (t+4) and its readers (t+5) are
// transitively gated behind this WG's later publishes => sentinel lands before
// fresh data, and no reader starts before sentinels are L3-visible.
__global__ __launch_bounds__(256, 1) void k_scan(
    const u16* __restrict__ obsT, const u16* __restrict__ WxT, const u16* __restrict__ WhT,
    const float* __restrict__ bvec, const float* __restrict__ c0f,
    u16* __restrict__ hp,
    u16* __restrict__ ys, float* __restrict__ outh, float* __restrict__ outc)
{
  __shared__ float zs[2][16*ZW];   // split-K partials
  __shared__ float cst[256];       // cell state slice
  __shared__ float bsl[64];        // bias slice
  __shared__ char pad_[98304];     // occupancy clamp: exactly 1 WG/CU

  const int tid = threadIdx.x, wv = tid >> 6, lane = tid & 63;
  const int wg = blockIdx.x, isl = wg & (GR-1), cg = wg >> 3;
  const int rb0 = isl*ROWS, S0 = cg*UN;
  ((volatile char*)pad_)[tid] = 0;

  const int kh = wv >> 1, ch = wv & 1;
  const int C0 = ch*32;
  const int lq = lane >> 4, l15 = lane & 15;
  const int arow = rb0 + l15;

  // B-fragments (compiler schedules any reloads into wait windows)
  const int j0 = C0 + l15, j1 = j0 + 16;
  const long w0 = (long)((j0 >> 4)*H_ + S0 + (j0 & 15));
  const long w1 = (long)((j1 >> 4)*H_ + S0 + (j1 & 15));
  bf16x8 wbx[4][2], wbh[8][2];
  #pragma unroll
  for (int ks = 0; ks < 4; ++ks) {
    const long k = (long)kh*128 + ks*32 + lq*8;
    wbx[ks][0] = *(const bf16x8*)(WxT + w0*NOBS + k);
    wbx[ks][1] = *(const bf16x8*)(WxT + w1*NOBS + k);
  }
  #pragma unroll
  for (int ks = 0; ks < 8; ++ks) {
    const long k = (long)kh*256 + ks*32 + lq*8;
    wbh[ks][0] = *(const bf16x8*)(WhT + w0*H_ + k);
    wbh[ks][1] = *(const bf16x8*)(WhT + w1*H_ + k);
  }

  cst[tid] = c0f[(rb0 + (tid >> 4))*H_ + S0 + (tid & 15)];
  if (tid < 64) bsl[tid] = bvec[(tid >> 4)*H_ + S0 + (tid & 15)];
  __syncthreads();

  const long fofs = (long)arow*H_ + kh*256 + lq*8;   // bulk fragment offset (u16)

  // obs fragments for t=0 (prefetched one step ahead thereafter)
  bf16x8 ax[4];
  {
    const u16* Ax = obsT + (long)arow*NOBS + kh*128 + lq*8;
    #pragma unroll
    for (int ks = 0; ks < 4; ++ks) ax[ks] = *(const bf16x8*)(Ax + ks*32);
  }

  for (int t = 0; t < T_; ++t) {
    f32x4 acc0 = {0.f,0.f,0.f,0.f}, acc1 = {0.f,0.f,0.f,0.f};

    // phase X: obs_t @ Wx — retires while producers' stores are in flight
    #pragma unroll
    for (int ks = 0; ks < 4; ++ks) {
      acc0 = __builtin_amdgcn_mfma_f32_16x16x32_bf16(ax[ks], wbx[ks][0], acc0, 0, 0, 0);
      acc1 = __builtin_amdgcn_mfma_f32_16x16x32_bf16(ax[ks], wbx[ks][1], acc1, 0, 0, 0);
    }

    // data-poll: 8 x 16B bulk load from plane t&7, retry while any word == SENT.
    // Pre-drain once so the in-loop vmcnt(0) counts only these loads (r11 lesson);
    // it also drains last step's publish/sentinel stores (the sentinel-drain edge).
    union { u32x4 u; bf16x8 v; } hf[8];
    {
      const u16* haddr = hp + ((long)(t & 7) << 16) + fofs;
      asm volatile("s_waitcnt vmcnt(0)" ::: "memory");
      int spin = 1 << 12;                    // bailout: fail visibly, never hang
      for (;;) {
        #pragma unroll
        for (int ks = 0; ks < 8; ++ks)
          asm volatile("global_load_dwordx4 %0, %1, off offset:%2 sc0 sc1"
                       : "=v"(hf[ks].u) : "v"(haddr), "i"(ks*64));
        asm volatile("s_waitcnt vmcnt(0)" ::: "memory");
        __builtin_amdgcn_sched_barrier(0);
        unsigned ready = 1u;
        #pragma unroll
        for (int ks = 0; ks < 8; ++ks)
          #pragma unroll
          for (int j = 0; j < 4; ++j)
            ready &= (hf[ks].u[j] != SENT) ? 1u : 0u;
        if (__all((int)ready)) break;
        if (--spin == 0) break;
      }
    }

    // obs prefetch for t+1 (plain loads; latency hides under phase H + epilogue)
    bf16x8 axn[4];
    {
      const int tn = (t+1 < T_) ? t+1 : t;
      const u16* Axn = obsT + ((long)tn*B_ + arow)*NOBS + kh*128 + lq*8;
      #pragma unroll
      for (int ks = 0; ks < 4; ++ks) axn[ks] = *(const bf16x8*)(Axn + ks*32);
    }

    // phase H: h @ Wh
    #pragma unroll
    for (int ks = 0; ks < 8; ++ks) {
      acc0 = __builtin_amdgcn_mfma_f32_16x16x32_bf16(hf[ks].v, wbh[ks][0], acc0, 0, 0, 0);
      acc1 = __builtin_amdgcn_mfma_f32_16x16x32_bf16(hf[ks].v, wbh[ks][1], acc1, 0, 0, 0);
    }
    #pragma unroll
    for (int ks = 0; ks < 4; ++ks) ax[ks] = axn[ks];

    // split-K partials to LDS  (D layout: col=lane&15, row=(lane>>4)*4+q)
    {
      const int zr0 = lq*4, zc = C0 + l15;
      #pragma unroll
      for (int q = 0; q < 4; ++q) {
        zs[kh][(zr0+q)*ZW + zc]      = acc0[q];
        zs[kh][(zr0+q)*ZW + zc + 16] = acc1[q];
      }
    }
    __syncthreads();

    // epilogue: 128 threads, 2 units each. PUBLISH = fire-and-forget data store.
    // No drain, no barrier, no flag. Sentinel pre-cleans plane (t+5)&7.
    if (tid < 128) {
      const int rr = tid >> 3, pp = tid & 7;
      float hv2[2], cn2[2];
      #pragma unroll
      for (int u = 0; u < 2; ++u) {
        const int sl = 2*pp + u;
        const float* z0 = &zs[0][rr*ZW];
        const float* z1 = &zs[1][rr*ZW];
        const float zi = z0[sl]    + z1[sl]    + bsl[sl];
        const float zf = z0[16+sl] + z1[16+sl] + bsl[16+sl];
        const float zg = z0[32+sl] + z1[32+sl] + bsl[32+sl];
        const float zo = z0[48+sl] + z1[48+sl] + bsl[48+sl];
        const float cv = cst[rr*16 + sl];
        const float cn = sigm(zf)*cv + sigm(zi)*tanh_f(zg);
        hv2[u] = sigm(zo)*tanh_f(cn);
        cn2[u] = cn;
        cst[rr*16 + sl] = cn;
      }
      const unsigned h01 = (unsigned)f2b(hv2[0]) | ((unsigned)f2b(hv2[1]) << 16);
      const int bq = rb0 + rr;
      const long wofs = (long)bq*H_ + S0 + 2*pp;
      if (t < T_-1)
        __hip_atomic_store((u32*)(hp + ((long)((t+1) & 7) << 16) + wofs), h01,
                           __ATOMIC_RELAXED, __HIP_MEMORY_SCOPE_AGENT);
      __hip_atomic_store((u32*)(hp + ((long)((t+5) & 7) << 16) + wofs), SENT,
                         __ATOMIC_RELAXED, __HIP_MEMORY_SCOPE_AGENT);
      *(u32*)(ys + ((long)bq*T_ + t)*H_ + S0 + 2*pp) = h01;
      if (t == T_-1) {
        outh[bq*H_ + S0 + 2*pp]     = hv2[0];
        outh[bq*H_ + S0 + 2*pp + 1] = hv2[1];
        outc[bq*H_ + S0 + 2*pp]     = cn2[0];
        outc[bq*H_ + S0 + 2*pp + 1] = cn2[1];
      }
    }
    // no trailing barrier: poll(t+1) passing implies own WG's epilogue published,
    // which is program-ordered after its zs(t) reads => zs WAR ordered (as r8).
  }
}

// ---------------- head ----------------
__global__ __launch_bounds__(256) void k_head(const u16* __restrict__ X, const u16* __restrict__ WoT,
    const float* __restrict__ bo, const float* __restrict__ amin, const float* __restrict__ amax,
    float* __restrict__ out)
{
  __shared__ u16 Ws[NACT*H_];
  __shared__ float sc[3*NACT];
  const int tid = threadIdx.x;
  #pragma unroll
  for (int q = 0; q < 8; ++q)
    ((float4*)Ws)[q*256 + tid] = ((const float4*)WoT)[q*256 + tid];
  if (tid < NACT) { sc[tid] = bo[tid]; sc[NACT+tid] = amin[tid]; sc[2*NACT+tid] = amax[tid]; }
  __syncthreads();
  const long r = (long)blockIdx.x*64 + (tid >> 2);
  const int c0 = (tid & 3)*8;
  float acc[8];
  #pragma unroll
  for (int c = 0; c < 8; ++c) acc[c] = 0.f;
  const u16* Arow = X + r*H_;
  for (int kc = 0; kc < H_/8; ++kc) {
    bf16x8 a = *(const bf16x8*)(Arow + kc*8);
    float av[8];
    #pragma unroll
    for (int j = 0; j < 8; ++j) av[j] = b2f((u16)a[j]);
    #pragma unroll
    for (int c = 0; c < 8; ++c) {
      bf16x8 w = *(const bf16x8*)(Ws + (c0+c)*H_ + kc*8);
      #pragma unroll
      for (int j = 0; j < 8; ++j) acc[c] += av[j] * b2f((u16)w[j]);
    }
  }
  #pragma unroll
  for (int c = 0; c < 8; ++c) {
    const int cc = c0 + c;
    const float y = acc[c] + sc[cc];
    const float tv = tanhf(y);
    out[r*NACT + cc] = 0.5f*(tv*(sc[2*NACT+cc]-sc[NACT+cc]) + (sc[2*NACT+cc]+sc[NACT+cc]));
  }
}

extern "C" void kernel_launch(void* const* d_in, const int* in_sizes, int n_in,
                              void* d_out, int out_size, void* d_ws, size_t ws_size,
                              hipStream_t stream) {
  const float* obs = (const float*)d_in[0];
  const float* h0  = (const float*)d_in[1];
  const float* c0  = (const float*)d_in[2];
  const float* Wx  = (const float*)d_in[3];
  const float* Wh  = (const float*)d_in[4];
  const float* bb  = (const float*)d_in[5];
  const float* W1  = (const float*)d_in[6];
  const float* b1  = (const float*)d_in[7];
  const float* W2  = (const float*)d_in[8];
  const float* b2  = (const float*)d_in[9];
  const float* Wo  = (const float*)d_in[10];
  const float* bo  = (const float*)d_in[11];
  const float* amin= (const float*)d_in[12];
  const float* amax= (const float*)d_in[13];

  char* ws = (char*)d_ws;
  // workspace layout (bytes), within the proven footprint. hp (8 planes x 128KiB
  // = 1 MiB) lives at the head of the dead t1 region (t1 written only after the
  // scan; hp dead once the scan ends — r9 proved this aliasing safe).
  u16* obsT  = (u16*)(ws + 0);                 // (T,B,NOBS) bf16, 32 MiB
  u16* ys    = (u16*)(ws + 33554432);          // (B,T,H) bf16, 64 MiB
  u16* t1    = (u16*)(ws + 100663296);         // 64 MiB
  u16* t2    = (u16*)(ws + 33554432);          // alias ys (dead after W1-GEMM)
  u16* hp    = (u16*)(ws + 100663296);         // 8 h planes, 1 MiB (in dead t1)
  u16* WxT   = (u16*)(ws + 167772160);         // (G4, NOBS)  1 MiB
  u16* WhT   = (u16*)(ws + 168820736);         // (G4, H)     2 MiB
  u16* W1T   = (u16*)(ws + 170917888);         // 0.5 MiB
  u16* W2T   = (u16*)(ws + 171442176);         // 0.5 MiB
  u16* WoT   = (u16*)(ws + 171966464);         // 64 KiB

  float* outA = (float*)d_out;
  float* outh = outA + (long)M_*NACT;
  float* outc = outh + B_*H_;

  k_cvt_obsT<<<M_*NOBS/8/256, 256, 0, stream>>>(obs, obsT);
  k_inith<<<1024, 256, 0, stream>>>(h0, hp);          // plane 0 = h0; 1..7 = SENT
  k_transpose<<<2048, 256, 0, stream>>>(Wx, WxT, NOBS, G4);
  k_transpose<<<4096, 256, 0, stream>>>(Wh, WhT, H_, G4);
  k_transpose<<<1024, 256, 0, stream>>>(W1, W1T, H_, H_);
  k_transpose<<<1024, 256, 0, stream>>>(W2, W2T, H_, H_);
  k_transpose<<<64,   256, 0, stream>>>(Wo, WoT, H_, NACT);

  // persistent scan: 256 co-resident WGs (1/CU), sentinel-in-data h exchange
  k_scan<<<256, 256, 0, stream>>>(obsT, WxT, WhT, bb, c0, hp, ys, outh, outc);

  // MLP head
  k_gemm_bt<1><<<(M_/128)*(H_/128), 256, 0, stream>>>(ys, W1T, t1, b1, M_, H_, H_);
  k_gemm_bt<1><<<(M_/128)*(H_/128), 256, 0, stream>>>(t1, W2T, t2, b2, M_, H_, H_);
  k_head<<<M_/64, 256, 0, stream>>>(t2, WoT, bo, amin, amax, outA);
}